// Round 11
// baseline (333.432 us; speedup 1.0000x reference)
//
#include <hip/hip_runtime.h>
#include <hip/hip_bf16.h>

#define HH 12
#define DD 64
#define NB1 28
#define NB2 52
#define NF 2
#define FB1 56           // NF*NB1
#define FB2 104          // NF*NB2
#define STRIDE_HD 768    // HH*DD
#define SCALEF 0.125f

typedef float f32x4 __attribute__((ext_vector_type(4)));
typedef float f32x16 __attribute__((ext_vector_type(16)));
typedef short bf16x8 __attribute__((ext_vector_type(8)));

#if __has_builtin(__builtin_amdgcn_exp2f)
#define EXP2(x) __builtin_amdgcn_exp2f(x)
#else
#define EXP2(x) __expf((x) * 0.6931471805599453f)
#endif

__device__ __forceinline__ unsigned short f2bf(float x) {
  union { float f; unsigned u; } c; c.f = x;
  unsigned r = c.u + 0x7fffu + ((c.u >> 16) & 1u);
  return (unsigned short)(r >> 16);
}
__device__ __forceinline__ float bf2f(unsigned short u) {
  union { unsigned u32v; float f; } c; c.u32v = ((unsigned)u) << 16; return c.f;
}

// ===========================================================================
// k_proj: 64-row x 64-out projection tiles + rope, outputs key-grouped.
// ===========================================================================
__global__ __launch_bounds__(256, 4)
void k_proj(const float* __restrict__ lk, const float* __restrict__ rq,
            const float* __restrict__ cosb, const float* __restrict__ sinb,
            const float* __restrict__ W_lkk, const float* __restrict__ b_lkk,
            const float* __restrict__ W_rqk, const float* __restrict__ b_rqk,
            const float* __restrict__ W_lkq, const float* __restrict__ b_lkq,
            const float* __restrict__ W_rqq, const float* __restrict__ b_rqq,
            float* __restrict__ Klg, float* __restrict__ Krg,
            float* __restrict__ ql, float* __restrict__ qr) {
  __shared__ __align__(16) float Wt[64][68];   // [d][e]
  __shared__ __align__(16) float xs[64][68];   // [r][d]
  __shared__ int srows[64];
  __shared__ int obase[64];

  const int tid = threadIdx.x;
  int bx = blockIdx.x;
  int path, h, c;
  if (bx < 552)       { path = 0; h = bx / 46; c = bx % 46; }
  else if (bx < 1104) { path = 1; bx -= 552;  h = bx / 46; c = bx % 46; }
  else if (bx < 1116) { path = 2; h = bx - 1104; c = 0; }
  else                { path = 3; bx -= 1116; h = bx >> 1; c = bx & 1; }

  const float* X  = (path == 1 || path == 3) ? rq : lk;
  const float* W  = (path == 0) ? W_lkk : (path == 1) ? W_rqk : (path == 2) ? W_lkq : W_rqq;
  const float* bb = (path == 0) ? b_lkk : (path == 1) ? b_rqk : (path == 2) ? b_lkq : b_rqq;
  float* out      = (path == 0) ? Klg : (path == 1) ? Krg : (path == 2) ? ql : qr;
  const int nrows = (path == 0 || path == 1) ? ((c == 45) ? 32 : 64)
                   : (path == 2) ? 56 : ((c == 1) ? 40 : 64);

  for (int idx = tid; idx < 4096; idx += 256)
    Wt[idx & 63][idx >> 6] = W[(size_t)h * 4096 + idx];
  if (tid < 64) {
    int rr = tid, s = 0, ob = 0;
    if (rr < nrows) {
      if (path == 0) {
        s = c * 64 + rr;
        int f = s / 1456, rem = s % 1456, b1 = rem / 52, b2 = rem % 52;
        ob = ((h * 56 + f * 28 + b1) * 52 + b2) * 64;
      } else if (path == 1) {
        s = c * 64 + rr;
        int f = s / 1456, rem = s % 1456, b1 = rem / 52, jj = rem % 52;
        ob = ((h * 104 + f * 52 + jj) * 28 + b1) * 64;
      } else if (path == 2) {
        int q = rr;
        s = (q / 28) * 1456 + (q % 28) * 52;
        ob = (h * 56 + q) * 64;
      } else {
        int q = c * 64 + rr;
        s = (q / 52) * 1456 + (q % 52);
        ob = (h * 104 + q) * 64;
      }
    }
    srows[rr] = s; obase[rr] = ob;
  }
  __syncthreads();
  for (int idx = tid; idx < 4096; idx += 256) {
    int r = idx >> 6, d = idx & 63;
    xs[r][d] = X[(size_t)srows[r] * STRIDE_HD + h * DD + d];
  }
  __syncthreads();

  const int it = tid >> 4, kt = tid & 15;
  f32x4 acc0 = {0,0,0,0}, acc1 = {0,0,0,0}, acc2 = {0,0,0,0}, acc3 = {0,0,0,0};
  #pragma unroll 4
  for (int d4 = 0; d4 < 16; ++d4) {
    f32x4 x0 = *(const f32x4*)&xs[4 * it][4 * d4];
    f32x4 x1 = *(const f32x4*)&xs[4 * it + 1][4 * d4];
    f32x4 x2 = *(const f32x4*)&xs[4 * it + 2][4 * d4];
    f32x4 x3 = *(const f32x4*)&xs[4 * it + 3][4 * d4];
    #pragma unroll
    for (int dd = 0; dd < 4; ++dd) {
      f32x4 wv = *(const f32x4*)&Wt[4 * d4 + dd][4 * kt];
      acc0 += x0[dd] * wv;
      acc1 += x1[dd] * wv;
      acc2 += x2[dd] * wv;
      acc3 += x3[dd] * wv;
    }
  }

  f32x4 bv;
  bv[0] = bb[h * 64 + 4 * kt];     bv[1] = bb[h * 64 + 4 * kt + 1];
  bv[2] = bb[h * 64 + 4 * kt + 2]; bv[3] = bb[h * 64 + 4 * kt + 3];
  #pragma unroll
  for (int rr = 0; rr < 4; ++rr) {
    int row = 4 * it + rr;
    if (row < nrows) {
      f32x4 o = (rr == 0) ? acc0 : (rr == 1) ? acc1 : (rr == 2) ? acc2 : acc3;
      o += bv;
      int s = srows[row];
      float c0 = cosb[s * 32 + 2 * kt],     s0 = sinb[s * 32 + 2 * kt];
      float c1 = cosb[s * 32 + 2 * kt + 1], s1 = sinb[s * 32 + 2 * kt + 1];
      f32x4 res;
      res[0] = o[0] * c0 - o[1] * s0;
      res[1] = o[1] * c0 + o[0] * s0;
      res[2] = o[2] * c1 - o[3] * s1;
      res[3] = o[3] * c1 + o[2] * s1;
      *(f32x4*)(out + obase[row] + 4 * kt) = res;
    }
  }
}

// ===========================================================================
// k_sv: per-(n,h) tiny SDPA (wide phases) for both paths + V bf16 re-layout
// ===========================================================================
struct SvShared {
  union {
    struct { float qv[64]; float sc[64]; float ps[64]; float ys[64]; float oe[64]; } s;
    float tile[52][68];
  } u;
};

template<int NK, int NG, int GD, int GMUL, int KSTR>
__device__ void sdpa_path(int n, int h, const float* __restrict__ X,
                          const float* __restrict__ Kg, const float* __restrict__ qb,
                          const float* __restrict__ cosb, const float* __restrict__ sinb,
                          const float* __restrict__ Wv, const float* __restrict__ bvv,
                          float* __restrict__ outb, SvShared& sm) {
  const int t = threadIdx.x;
  const int f = n / GD, g = n % GD;
  const int s_base = f * (NB1 * NB2) + g * GMUL;

  if (t < 64) sm.u.s.qv[t] = qb[(size_t)(h * NG + n) * 64 + t];
  __syncthreads();

  if (t < NK * 4) {
    int r = t >> 2, part = t & 3;
    const float4* kr = (const float4*)(Kg + ((size_t)(h * NG + n) * NK + r) * 64 + part * 16);
    const float4* q4 = (const float4*)(sm.u.s.qv + part * 16);
    float p = 0.f;
    #pragma unroll
    for (int i = 0; i < 4; ++i) {
      float4 kv = kr[i], qv4 = q4[i];
      p += kv.x * qv4.x + kv.y * qv4.y + kv.z * qv4.z + kv.w * qv4.w;
    }
    p += __shfl_xor(p, 1); p += __shfl_xor(p, 2);
    if (part == 0) sm.u.s.sc[r] = p * SCALEF;
  }
  __syncthreads();

  if (t < 64) {
    float v = (t < NK) ? sm.u.s.sc[t] : -1e30f;
    float mx = v;
    for (int o = 32; o; o >>= 1) mx = fmaxf(mx, __shfl_xor(mx, o));
    float e = (t < NK) ? __expf(v - mx) : 0.f;
    float sum = e;
    for (int o = 32; o; o >>= 1) sum += __shfl_xor(sum, o);
    sm.u.s.ps[t] = (t < NK) ? e / sum : 0.f;
  }
  __syncthreads();

  {
    int d = t >> 2, g4 = t & 3;
    constexpr int RPG = NK / 4;
    float yp = 0.f;
    #pragma unroll 4
    for (int rr = 0; rr < RPG; ++rr) {
      int r = g4 * RPG + rr;
      yp += sm.u.s.ps[r] * X[(size_t)(s_base + r * KSTR) * STRIDE_HD + h * DD + d];
    }
    yp += __shfl_xor(yp, 1); yp += __shfl_xor(yp, 2);
    if (g4 == 0) sm.u.s.ys[d] = yp;
  }
  __syncthreads();

  {
    int e = t >> 2, part = t & 3;
    const float4* wr = (const float4*)(Wv + (size_t)h * 4096 + e * 64 + part * 16);
    const float4* y4 = (const float4*)(sm.u.s.ys + part * 16);
    float p = 0.f;
    #pragma unroll
    for (int i = 0; i < 4; ++i) {
      float4 wv = wr[i], yv = y4[i];
      p += wv.x * yv.x + wv.y * yv.y + wv.z * yv.z + wv.w * yv.w;
    }
    p += __shfl_xor(p, 1); p += __shfl_xor(p, 2);
    if (part == 0) sm.u.s.oe[e] = p + bvv[h * 64 + e];
  }
  __syncthreads();

  if (t < 32) {
    float co = cosb[s_base * 32 + t], si = sinb[s_base * 32 + t];
    float o0 = sm.u.s.oe[2 * t], o1 = sm.u.s.oe[2 * t + 1];
    outb[(size_t)n * STRIDE_HD + h * DD + 2 * t]     = o0 * co - o1 * si;
    outb[(size_t)n * STRIDE_HD + h * DD + 2 * t + 1] = o1 * co + o0 * si;
  }
}

// v (S,H,D) f32 -> vb2[h][fk][l8][d][li] bf16 (l = l8*8+li, l>=52 zero)
__device__ void vb_path(int fk, int h, const float* __restrict__ v,
                        unsigned short* __restrict__ vb2, SvShared& sm) {
  const int tid = threadIdx.x;
  for (int idx = tid; idx < NB2 * DD; idx += 256) {
    int l = idx >> 6, d = idx & 63;
    sm.u.tile[l][d] = v[(size_t)(fk * NB2 + l) * STRIDE_HD + h * DD + d];
  }
  __syncthreads();
  for (int idx = tid; idx < 512; idx += 256) {
    int l8 = idx >> 6, d = idx & 63;
    unsigned short tmp[8];
    #pragma unroll
    for (int li = 0; li < 8; ++li) {
      int l = l8 * 8 + li;
      tmp[li] = (l < NB2) ? f2bf(sm.u.tile[l][d]) : (unsigned short)0;
    }
    bf16x8* dst = (bf16x8*)(vb2 + (((size_t)(h * FB1 + fk) * 8 + l8) * 64 + d) * 8);
    *dst = *(bf16x8*)tmp;
  }
}

__global__ __launch_bounds__(256)
void k_sv(const float* __restrict__ lk, const float* __restrict__ rq,
          const float* __restrict__ v,
          const float* __restrict__ cosb, const float* __restrict__ sinb,
          const float* __restrict__ Klg, const float* __restrict__ Krg,
          const float* __restrict__ ql, const float* __restrict__ qr,
          const float* __restrict__ W_lkv, const float* __restrict__ b_lkv,
          const float* __restrict__ W_rqv, const float* __restrict__ b_rqv,
          float* __restrict__ lk_out, float* __restrict__ rq_out,
          unsigned short* __restrict__ vb2) {
  __shared__ SvShared sm;
  const int bx = blockIdx.x;
  if (bx < 672) {
    sdpa_path<52, 56, 28, 52, 1>(bx % 56, bx / 56, lk, Klg, ql, cosb, sinb,
                                 W_lkv, b_lkv, lk_out, sm);
  } else if (bx < 1920) {
    int id = bx - 672;
    sdpa_path<28, 104, 52, 1, 52>(id % 104, id / 104, rq, Krg, qr, cosb, sinb,
                                  W_rqv, b_rqv, rq_out, sm);
  } else {
    int id = bx - 1920;
    vb_path(id % 56, id / 56, v, vb2, sm);
  }
}

// ===========================================================================
// MID (MFMA, hi/lo bf16 split), single merged launch.
// ===========================================================================
struct MgL { unsigned short Yhi[64][64];  unsigned short Ylo[64][64];
             unsigned short Xhi[64][64];  unsigned short Xlo[64][64]; };
struct MgR { unsigned short Yhi[128][64]; unsigned short Ylo[128][64];
             unsigned short Xhi[32][64];  unsigned short Xlo[32][64]; };
union MgShared { MgL L; MgR R; };

__global__ __launch_bounds__(256, 4)
void k_midg(const float* __restrict__ lq, const float* __restrict__ rk,
            const float* __restrict__ lk_out, const float* __restrict__ rq_out,
            const float* __restrict__ cosb, const float* __restrict__ sinb,
            float* __restrict__ LbufN, float* __restrict__ Rbuf) {
  __shared__ __align__(16) MgShared sh;
  const int tid = threadIdx.x;
  const int lane = tid & 63, w = tid >> 6;
  const int hi = lane >> 5, arow = lane & 31;
  int bx = blockIdx.x;

  if (bx < 552) {
    const int h = bx / 46, pt = bx % 46;
    const int rowbase = pt * 64;
    for (int idx = tid; idx < 2048; idx += 256) {           // Y (56 valid)
      int q = idx >> 5, m = idx & 31;
      float y0 = 0.f, y1 = 0.f;
      if (q < 56) {
        float2 yv = *(const float2*)(lk_out + (size_t)q * STRIDE_HD + h * DD + 2 * m);
        y0 = yv.x; y1 = yv.y;
      }
      unsigned short h0 = f2bf(y0), h1 = f2bf(y1);
      unsigned short l0 = f2bf(y0 - bf2f(h0)), l1 = f2bf(y1 - bf2f(h1));
      int ms2 = m ^ ((q & 7) << 2);
      ((unsigned*)sh.L.Yhi[q])[ms2] = (unsigned)h0 | ((unsigned)h1 << 16);
      ((unsigned*)sh.L.Ylo[q])[ms2] = (unsigned)l0 | ((unsigned)l1 << 16);
    }
    for (int idx = tid; idx < 2048; idx += 256) {           // X + rope
      int r = idx >> 5, m = idx & 31;
      int srow = rowbase + r;
      float o0 = 0.f, o1 = 0.f;
      if (srow < 2912) {
        float2 xv = *(const float2*)(lq + (size_t)srow * STRIDE_HD + h * DD + 2 * m);
        float co = cosb[srow * 32 + m], si = sinb[srow * 32 + m];
        o0 = xv.x * co - xv.y * si;
        o1 = xv.y * co + xv.x * si;
      }
      unsigned short h0 = f2bf(o0), h1 = f2bf(o1);
      unsigned short l0 = f2bf(o0 - bf2f(h0)), l1 = f2bf(o1 - bf2f(h1));
      int ms2 = m ^ ((r & 7) << 2);
      ((unsigned*)sh.L.Xhi[r])[ms2] = (unsigned)h0 | ((unsigned)h1 << 16);
      ((unsigned*)sh.L.Xlo[r])[ms2] = (unsigned)l0 | ((unsigned)l1 << 16);
    }
    __syncthreads();

    const int xt = w >> 1, qt = w & 1;
    const int brow = qt * 32 + arow;
    const int bswz = (brow & 7) << 3;
    const int xrow = xt * 32 + arow;
    const int aswz = (xrow & 7) << 3;
    f32x16 acc = {0.f,0.f,0.f,0.f,0.f,0.f,0.f,0.f,0.f,0.f,0.f,0.f,0.f,0.f,0.f,0.f};
    #pragma unroll
    for (int ks = 0; ks < 4; ++ks) {
      int kbB = (ks * 16 + hi * 8) ^ bswz;
      int kbA = (ks * 16 + hi * 8) ^ aswz;
      bf16x8 Bhi = *(const bf16x8*)&sh.L.Yhi[brow][kbB];
      bf16x8 Blo = *(const bf16x8*)&sh.L.Ylo[brow][kbB];
      bf16x8 Ahi = *(const bf16x8*)&sh.L.Xhi[xrow][kbA];
      bf16x8 Alo = *(const bf16x8*)&sh.L.Xlo[xrow][kbA];
      acc = __builtin_amdgcn_mfma_f32_32x32x16_bf16(Ahi, Bhi, acc, 0, 0, 0);
      acc = __builtin_amdgcn_mfma_f32_32x32x16_bf16(Ahi, Blo, acc, 0, 0, 0);
      acc = __builtin_amdgcn_mfma_f32_32x32x16_bf16(Alo, Bhi, acc, 0, 0, 0);
    }
    int col = qt * 32 + arow;
    if (col < 56) {
      #pragma unroll
      for (int rg = 0; rg < 16; ++rg) {
        int P = rowbase + xt * 32 + (rg & 3) + 8 * (rg >> 2) + 4 * hi;
        if (P < 2912)
          LbufN[((size_t)h * 2912 + P) * 56 + col] = acc[rg];
      }
    }
  } else {
    bx -= 552;
    const int h = bx / 91, pt = bx % 91;
    const int rowbase = pt * 32;
    for (int idx = tid; idx < 4096; idx += 256) {           // Y (104 valid)
      int q = idx >> 5, m = idx & 31;
      float y0 = 0.f, y1 = 0.f;
      if (q < 104) {
        float2 yv = *(const float2*)(rq_out + (size_t)q * STRIDE_HD + h * DD + 2 * m);
        y0 = yv.x; y1 = yv.y;
      }
      unsigned short h0 = f2bf(y0), h1 = f2bf(y1);
      unsigned short l0 = f2bf(y0 - bf2f(h0)), l1 = f2bf(y1 - bf2f(h1));
      int ms2 = m ^ ((q & 7) << 2);
      ((unsigned*)sh.R.Yhi[q])[ms2] = (unsigned)h0 | ((unsigned)h1 << 16);
      ((unsigned*)sh.R.Ylo[q])[ms2] = (unsigned)l0 | ((unsigned)l1 << 16);
    }
    for (int idx = tid; idx < 1024; idx += 256) {           // X + rope
      int r = idx >> 5, m = idx & 31;
      int srow = rowbase + r;
      float2 xv = *(const float2*)(rk + (size_t)srow * STRIDE_HD + h * DD + 2 * m);
      float co = cosb[srow * 32 + m], si = sinb[srow * 32 + m];
      float o0 = xv.x * co - xv.y * si;
      float o1 = xv.y * co + xv.x * si;
      unsigned short h0 = f2bf(o0), h1 = f2bf(o1);
      unsigned short l0 = f2bf(o0 - bf2f(h0)), l1 = f2bf(o1 - bf2f(h1));
      int ms2 = m ^ ((r & 7) << 2);
      ((unsigned*)sh.R.Xhi[r])[ms2] = (unsigned)h0 | ((unsigned)h1 << 16);
      ((unsigned*)sh.R.Xlo[r])[ms2] = (unsigned)l0 | ((unsigned)l1 << 16);
    }
    __syncthreads();

    const int brow = w * 32 + arow;
    const int bswz = (brow & 7) << 3;
    const int aswz = (arow & 7) << 3;
    f32x16 acc = {0.f,0.f,0.f,0.f,0.f,0.f,0.f,0.f,0.f,0.f,0.f,0.f,0.f,0.f,0.f,0.f};
    #pragma unroll
    for (int ks = 0; ks < 4; ++ks) {
      int kbB = (ks * 16 + hi * 8) ^ bswz;
      int kbA = (ks * 16 + hi * 8) ^ aswz;
      bf16x8 Bhi = *(const bf16x8*)&sh.R.Yhi[brow][kbB];
      bf16x8 Blo = *(const bf16x8*)&sh.R.Ylo[brow][kbB];
      bf16x8 Ahi = *(const bf16x8*)&sh.R.Xhi[arow][kbA];
      bf16x8 Alo = *(const bf16x8*)&sh.R.Xlo[arow][kbA];
      acc = __builtin_amdgcn_mfma_f32_32x32x16_bf16(Ahi, Bhi, acc, 0, 0, 0);
      acc = __builtin_amdgcn_mfma_f32_32x32x16_bf16(Ahi, Blo, acc, 0, 0, 0);
      acc = __builtin_amdgcn_mfma_f32_32x32x16_bf16(Alo, Bhi, acc, 0, 0, 0);
    }
    int cq = w * 32 + arow;
    if (cq < 104) {
      int aa = (cq >= 52) ? 1 : 0;
      int jj = cq - aa * 52;
      float* rowp = Rbuf + ((size_t)((h * 2 + aa) * 52 + jj)) * 2912 + rowbase + 4 * hi;
      #pragma unroll
      for (int q4 = 0; q4 < 4; ++q4) {
        f32x4 res = {acc[4 * q4], acc[4 * q4 + 1], acc[4 * q4 + 2], acc[4 * q4 + 3]};
        *(f32x4*)(rowp + 8 * q4) = res;
      }
    }
  }
}

// ===========================================================================
// MAIN: factorized flash attention, 1 j per block, L per-t scalar loads,
// V double-buffered in registers (8 bf16x8 per tile, even/odd buffers).
// ===========================================================================
__device__ __forceinline__ bf16x8 make_p8(float Lv, float nm, float4 ra, float4 rb,
                                          int ks, int hi, float& lsum) {
  float p0 = EXP2(fmaf(Lv, ra.x, nm));
  float p1 = EXP2(fmaf(Lv, ra.y, nm));
  float p2 = EXP2(fmaf(Lv, ra.z, nm));
  float p3 = EXP2(fmaf(Lv, ra.w, nm));
  float p4 = EXP2(fmaf(Lv, rb.x, nm));
  float p5 = EXP2(fmaf(Lv, rb.y, nm));
  float p6 = EXP2(fmaf(Lv, rb.z, nm));
  float p7 = EXP2(fmaf(Lv, rb.w, nm));
  if (ks == 3) {
    if (hi == 0) { p4 = 0.f; p5 = 0.f; p6 = 0.f; p7 = 0.f; }
    else { p0 = 0.f; p1 = 0.f; p2 = 0.f; p3 = 0.f;
           p4 = 0.f; p5 = 0.f; p6 = 0.f; p7 = 0.f; }
  }
  lsum += ((p0 + p1) + (p2 + p3)) + ((p4 + p5) + (p6 + p7));
  union { bf16x8 v8; __hip_bfloat162 h2[4]; } pk;
  pk.h2[0] = __float22bfloat162_rn(make_float2(p0, p1));
  pk.h2[1] = __float22bfloat162_rn(make_float2(p2, p3));
  pk.h2[2] = __float22bfloat162_rn(make_float2(p4, p5));
  pk.h2[3] = __float22bfloat162_rn(make_float2(p6, p7));
  return pk.v8;
}

__global__ __launch_bounds__(256, 4)
void k_main(const float* __restrict__ LbufN, const float* __restrict__ Rbuf,
            const unsigned short* __restrict__ vb2, float* __restrict__ outp) {
  const int bid0 = blockIdx.x;
  const int bid = (bid0 & 7) * 156 + (bid0 >> 3);   // 1248 = 8*156, XCD-chunked
  const int h = bid / (NF * NB2);
  const int rem = bid % (NF * NB2);
  const int a = rem / NB2, j = rem % NB2;
  const int tid = threadIdx.x;
  const int lane = tid & 63;
  const int w = tid >> 6;
  const int row = lane & 31;
  const int hi = lane >> 5;

  __shared__ __align__(16) union { float Rs[56][64]; float epil[4][16][64]; } ms;
  __shared__ float Rmx[FB1], Rmn[FB1], pmax[4][32], els[4][32];

  // Rs staging (52 valid l per fk; 52..63 garbage, masked at ks==3)
  const float* Rrow = Rbuf + ((size_t)(h * 2 + a) * 52 + j) * 2912;
  for (int idx = tid; idx < 728; idx += 256) {
    int fk = idx / 13, lc = idx % 13;
    float4 vv = ((const float4*)Rrow)[idx];
    *(float4*)&ms.Rs[fk][lc * 4] = vv;
  }
  __syncthreads();

  if (tid < 224) {                                  // col max/min of R
    int fk = tid >> 2, part = tid & 3;
    float mx = -1e30f, mn = 1e30f;
    for (int l = part * 13; l < part * 13 + 13; ++l) {
      float x = ms.Rs[fk][l];
      mx = fmaxf(mx, x); mn = fminf(mn, x);
    }
    mx = fmaxf(mx, __shfl_xor(mx, 1)); mn = fminf(mn, __shfl_xor(mn, 1));
    mx = fmaxf(mx, __shfl_xor(mx, 2)); mn = fminf(mn, __shfl_xor(mn, 2));
    if (part == 0) { Rmx[fk] = mx; Rmn[fk] = mn; }
  }
  __syncthreads();                                  // Rmx/Rmn ready

  const float SC = SCALEF * 1.44269504f;
  const float* Lrow = LbufN + ((size_t)h * 2912 + a * 1456 + row * 52 + j) * 56 + w * 14;
  const bool rv = (row < NB1);

  // exact row max: per-lane partial over this wave's 14 fk, combine across waves
  {
    float pm = -1e30f;
    #pragma unroll
    for (int t = 0; t < 14; ++t) {
      int fk = w * 14 + t;
      float Lv = rv ? Lrow[t] * SC : 0.f;
      pm = fmaxf(pm, fmaxf(Lv * Rmx[fk], Lv * Rmn[fk]));
    }
    if (hi == 0) pmax[w][row] = pm;
  }
  __syncthreads();
  const float m2 = fmaxf(fmaxf(pmax[0][row], pmax[1][row]),
                         fmaxf(pmax[2][row], pmax[3][row]));
  const float nm = -m2;

  const bf16x8* vw = (const bf16x8*)vb2 + (size_t)h * 28672 + hi * 64 + row;

  f32x16 acc0 = {0.f,0.f,0.f,0.f,0.f,0.f,0.f,0.f,0.f,0.f,0.f,0.f,0.f,0.f,0.f,0.f};
  f32x16 acc1 = acc0;
  float lsum = 0.f;

#define LOADV(P, T)                                                             \
  {                                                                             \
    const bf16x8* vp_ = vw + (size_t)(w * 14 + (T)) * 512;                      \
    P##0 = vp_[0];   P##1 = vp_[32];  P##2 = vp_[128]; P##3 = vp_[160];         \
    P##4 = vp_[256]; P##5 = vp_[288]; P##6 = vp_[384]; P##7 = vp_[416];         \
  }

#define KSTEP(T, KS, V0, V1)                                                    \
  {                                                                             \
    const int fk_ = w * 14 + (T);                                               \
    const int k0_ = (KS) * 16 + hi * 8;                                         \
    float4 ra = *(const float4*)&ms.Rs[fk_][k0_];                               \
    float4 rb = *(const float4*)&ms.Rs[fk_][k0_ + 4];                           \
    bf16x8 pk = make_p8(Lvt, nm, ra, rb, (KS), hi, lsum);                       \
    acc0 = __builtin_amdgcn_mfma_f32_32x32x16_bf16(pk, V0, acc0, 0, 0, 0);      \
    acc1 = __builtin_amdgcn_mfma_f32_32x32x16_bf16(pk, V1, acc1, 0, 0, 0);      \
  }

#define COMPUTE_T(T, P)                                                         \
  {                                                                             \
    const float Lvt = rv ? Lrow[(T)] * SC : 0.f;                                \
    KSTEP(T, 0, P##0, P##1)                                                     \
    KSTEP(T, 1, P##2, P##3)                                                     \
    KSTEP(T, 2, P##4, P##5)                                                     \
    KSTEP(T, 3, P##6, P##7)                                                     \
  }

  {
    bf16x8 va0, va1, va2, va3, va4, va5, va6, va7;
    bf16x8 vb0, vb1, vb2_, vb3, vb4, vb5, vb6, vb7;
    LOADV(va, 0)
    #pragma unroll
    for (int t = 0; t < 14; t += 2) {
      { const bf16x8* vp_ = vw + (size_t)(w * 14 + t + 1) * 512;
        vb0 = vp_[0];   vb1 = vp_[32];  vb2_ = vp_[128]; vb3 = vp_[160];
        vb4 = vp_[256]; vb5 = vp_[288]; vb6 = vp_[384];  vb7 = vp_[416]; }
      COMPUTE_T(t, va)
      if (t + 2 < 14) LOADV(va, t + 2)
      {
        const float Lvt = rv ? Lrow[t + 1] * SC : 0.f;
        KSTEP(t + 1, 0, vb0, vb1)
        KSTEP(t + 1, 1, vb2_, vb3)
        KSTEP(t + 1, 2, vb4, vb5)
        KSTEP(t + 1, 3, vb6, vb7)
      }
    }
  }
#undef LOADV
#undef KSTEP
#undef COMPUTE_T

  lsum += __shfl_xor(lsum, 32);
  if (lane < 32) els[w][lane] = lsum;
  __syncthreads();                                  // Rs reads done; els visible

  // epilogue: 2 rounds (d-halves) of 4-segment reduction through LDS
  #pragma unroll
  for (int half = 0; half < 2; ++half) {
    if (half) __syncthreads();
    #pragma unroll
    for (int r = 0; r < 16; ++r)
      ms.epil[w][r][lane] = half ? acc1[r] : acc0[r];
    __syncthreads();
    #pragma unroll
    for (int q = 0; q < 4; ++q) {
      int r = w + q * 4;
      int elane = tid & 63;
      float val = ms.epil[0][r][elane] + ms.epil[1][r][elane]
                + ms.epil[2][r][elane] + ms.epil[3][r][elane];
      int irow = (r & 3) + 8 * (r >> 2) + 4 * (elane >> 5);
      if (irow < NB1) {
        float li = 1.0f / (els[0][irow] + els[1][irow] + els[2][irow] + els[3][irow]);
        int srow = a * (NB1 * NB2) + irow * NB2 + j;
        int d = half * 32 + (elane & 31);
        outp[(size_t)srow * STRIDE_HD + h * DD + d] = val * li;
      }
    }
  }
}

// ---------------------------------------------------------------------------
extern "C" void kernel_launch(void* const* d_in, const int* in_sizes, int n_in,
                              void* d_out, int out_size, void* d_ws, size_t ws_size,
                              hipStream_t stream) {
  (void)in_sizes; (void)n_in; (void)out_size; (void)ws_size;
  const float* lq   = (const float*)d_in[0];
  const float* lk   = (const float*)d_in[1];
  const float* rq   = (const float*)d_in[2];
  const float* rk   = (const float*)d_in[3];
  const float* v    = (const float*)d_in[4];
  const float* cosb = (const float*)d_in[5];
  const float* sinb = (const float*)d_in[6];
  const float* W_lkq = (const float*)d_in[7];  const float* b_lkq = (const float*)d_in[8];
  const float* W_lkk = (const float*)d_in[9];  const float* b_lkk = (const float*)d_in[10];
  const float* W_lkv = (const float*)d_in[11]; const float* b_lkv = (const float*)d_in[12];
  const float* W_rqq = (const float*)d_in[13]; const float* b_rqq = (const float*)d_in[14];
  const float* W_rqk = (const float*)d_in[15]; const float* b_rqk = (const float*)d_in[16];
  const float* W_rqv = (const float*)d_in[17]; const float* b_rqv = (const float*)d_in[18];

  float* ws = (float*)d_ws;
  float* lk_out = ws;                                   // 43008
  float* rq_out = ws + 43008;                           // 79872
  float* LbufN  = ws + 122880;                          // 1956864 (12*2912*56)
  float* Rbuf   = ws + 2079744;                         // 3634176
  unsigned short* vb2 = (unsigned short*)(ws + 5713920);// 2752512 shorts
  float* ql     = ws + 7090176;                         // 43008
  float* qr     = ws + 7133184;                         // 79872
  // Klg/Krg alias the LbufN/Rbuf space (dead before k_midg writes them)
  float* Klg = LbufN;                                   // 2236416
  float* Krg = LbufN + 2236416;                         // 2236416 (ends < Rbuf end)

  k_proj<<<1140, 256, 0, stream>>>(lk, rq, cosb, sinb,
      W_lkk, b_lkk, W_rqk, b_rqk, W_lkq, b_lkq, W_rqq, b_rqq,
      Klg, Krg, ql, qr);
  k_sv<<<2592, 256, 0, stream>>>(lk, rq, v, cosb, sinb, Klg, Krg, ql, qr,
      W_lkv, b_lkv, W_rqv, b_rqv, lk_out, rq_out, vb2);
  k_midg<<<1644, 256, 0, stream>>>(lq, rk, lk_out, rq_out, cosb, sinb, LbufN, Rbuf);
  k_main<<<1248, 256, 0, stream>>>(LbufN, Rbuf, vb2, (float*)d_out);
}

// Round 12
// 99.148 us; speedup vs baseline: 3.3630x; 3.3630x over previous
//
#include <hip/hip_runtime.h>
#include <hip/hip_bf16.h>

#define HH 12
#define DD 64
#define NB1 28
#define NB2 52
#define NF 2
#define FB1 56           // NF*NB1
#define FB2 104          // NF*NB2
#define STRIDE_HD 768    // HH*DD
#define SCALEF 0.125f

typedef float f32x4 __attribute__((ext_vector_type(4)));
typedef float f32x16 __attribute__((ext_vector_type(16)));
typedef short bf16x8 __attribute__((ext_vector_type(8)));

#if __has_builtin(__builtin_amdgcn_exp2f)
#define EXP2(x) __builtin_amdgcn_exp2f(x)
#else
#define EXP2(x) __expf((x) * 0.6931471805599453f)
#endif

__device__ __forceinline__ unsigned short f2bf(float x) {
  union { float f; unsigned u; } c; c.f = x;
  unsigned r = c.u + 0x7fffu + ((c.u >> 16) & 1u);
  return (unsigned short)(r >> 16);
}
__device__ __forceinline__ float bf2f(unsigned short u) {
  union { unsigned u32v; float f; } c; c.u32v = ((unsigned)u) << 16; return c.f;
}

// ===========================================================================
// k_proj: 64-row x 64-out projection tiles + rope, outputs key-grouped.
// ===========================================================================
__global__ __launch_bounds__(256, 4)
void k_proj(const float* __restrict__ lk, const float* __restrict__ rq,
            const float* __restrict__ cosb, const float* __restrict__ sinb,
            const float* __restrict__ W_lkk, const float* __restrict__ b_lkk,
            const float* __restrict__ W_rqk, const float* __restrict__ b_rqk,
            const float* __restrict__ W_lkq, const float* __restrict__ b_lkq,
            const float* __restrict__ W_rqq, const float* __restrict__ b_rqq,
            float* __restrict__ Klg, float* __restrict__ Krg,
            float* __restrict__ ql, float* __restrict__ qr) {
  __shared__ __align__(16) float Wt[64][68];   // [d][e]
  __shared__ __align__(16) float xs[64][68];   // [r][d]
  __shared__ int srows[64];
  __shared__ int obase[64];

  const int tid = threadIdx.x;
  int bx = blockIdx.x;
  int path, h, c;
  if (bx < 552)       { path = 0; h = bx / 46; c = bx % 46; }
  else if (bx < 1104) { path = 1; bx -= 552;  h = bx / 46; c = bx % 46; }
  else if (bx < 1116) { path = 2; h = bx - 1104; c = 0; }
  else                { path = 3; bx -= 1116; h = bx >> 1; c = bx & 1; }

  const float* X  = (path == 1 || path == 3) ? rq : lk;
  const float* W  = (path == 0) ? W_lkk : (path == 1) ? W_rqk : (path == 2) ? W_lkq : W_rqq;
  const float* bb = (path == 0) ? b_lkk : (path == 1) ? b_rqk : (path == 2) ? b_lkq : b_rqq;
  float* out      = (path == 0) ? Klg : (path == 1) ? Krg : (path == 2) ? ql : qr;
  const int nrows = (path == 0 || path == 1) ? ((c == 45) ? 32 : 64)
                   : (path == 2) ? 56 : ((c == 1) ? 40 : 64);

  for (int idx = tid; idx < 4096; idx += 256)
    Wt[idx & 63][idx >> 6] = W[(size_t)h * 4096 + idx];
  if (tid < 64) {
    int rr = tid, s = 0, ob = 0;
    if (rr < nrows) {
      if (path == 0) {
        s = c * 64 + rr;
        int f = s / 1456, rem = s % 1456, b1 = rem / 52, b2 = rem % 52;
        ob = ((h * 56 + f * 28 + b1) * 52 + b2) * 64;
      } else if (path == 1) {
        s = c * 64 + rr;
        int f = s / 1456, rem = s % 1456, b1 = rem / 52, jj = rem % 52;
        ob = ((h * 104 + f * 52 + jj) * 28 + b1) * 64;
      } else if (path == 2) {
        int q = rr;
        s = (q / 28) * 1456 + (q % 28) * 52;
        ob = (h * 56 + q) * 64;
      } else {
        int q = c * 64 + rr;
        s = (q / 52) * 1456 + (q % 52);
        ob = (h * 104 + q) * 64;
      }
    }
    srows[rr] = s; obase[rr] = ob;
  }
  __syncthreads();
  for (int idx = tid; idx < 4096; idx += 256) {
    int r = idx >> 6, d = idx & 63;
    xs[r][d] = X[(size_t)srows[r] * STRIDE_HD + h * DD + d];
  }
  __syncthreads();

  const int it = tid >> 4, kt = tid & 15;
  f32x4 acc0 = {0,0,0,0}, acc1 = {0,0,0,0}, acc2 = {0,0,0,0}, acc3 = {0,0,0,0};
  #pragma unroll 4
  for (int d4 = 0; d4 < 16; ++d4) {
    f32x4 x0 = *(const f32x4*)&xs[4 * it][4 * d4];
    f32x4 x1 = *(const f32x4*)&xs[4 * it + 1][4 * d4];
    f32x4 x2 = *(const f32x4*)&xs[4 * it + 2][4 * d4];
    f32x4 x3 = *(const f32x4*)&xs[4 * it + 3][4 * d4];
    #pragma unroll
    for (int dd = 0; dd < 4; ++dd) {
      f32x4 wv = *(const f32x4*)&Wt[4 * d4 + dd][4 * kt];
      acc0 += x0[dd] * wv;
      acc1 += x1[dd] * wv;
      acc2 += x2[dd] * wv;
      acc3 += x3[dd] * wv;
    }
  }

  f32x4 bv;
  bv[0] = bb[h * 64 + 4 * kt];     bv[1] = bb[h * 64 + 4 * kt + 1];
  bv[2] = bb[h * 64 + 4 * kt + 2]; bv[3] = bb[h * 64 + 4 * kt + 3];
  #pragma unroll
  for (int rr = 0; rr < 4; ++rr) {
    int row = 4 * it + rr;
    if (row < nrows) {
      f32x4 o = (rr == 0) ? acc0 : (rr == 1) ? acc1 : (rr == 2) ? acc2 : acc3;
      o += bv;
      int s = srows[row];
      float c0 = cosb[s * 32 + 2 * kt],     s0 = sinb[s * 32 + 2 * kt];
      float c1 = cosb[s * 32 + 2 * kt + 1], s1 = sinb[s * 32 + 2 * kt + 1];
      f32x4 res;
      res[0] = o[0] * c0 - o[1] * s0;
      res[1] = o[1] * c0 + o[0] * s0;
      res[2] = o[2] * c1 - o[3] * s1;
      res[3] = o[3] * c1 + o[2] * s1;
      *(f32x4*)(out + obase[row] + 4 * kt) = res;
    }
  }
}

// ===========================================================================
// k_sv: per-(n,h) tiny SDPA (wide phases) for both paths + V bf16 re-layout
// ===========================================================================
struct SvShared {
  union {
    struct { float qv[64]; float sc[64]; float ps[64]; float ys[64]; float oe[64]; } s;
    float tile[52][68];
  } u;
};

template<int NK, int NG, int GD, int GMUL, int KSTR>
__device__ void sdpa_path(int n, int h, const float* __restrict__ X,
                          const float* __restrict__ Kg, const float* __restrict__ qb,
                          const float* __restrict__ cosb, const float* __restrict__ sinb,
                          const float* __restrict__ Wv, const float* __restrict__ bvv,
                          float* __restrict__ outb, SvShared& sm) {
  const int t = threadIdx.x;
  const int f = n / GD, g = n % GD;
  const int s_base = f * (NB1 * NB2) + g * GMUL;

  if (t < 64) sm.u.s.qv[t] = qb[(size_t)(h * NG + n) * 64 + t];
  __syncthreads();

  if (t < NK * 4) {
    int r = t >> 2, part = t & 3;
    const float4* kr = (const float4*)(Kg + ((size_t)(h * NG + n) * NK + r) * 64 + part * 16);
    const float4* q4 = (const float4*)(sm.u.s.qv + part * 16);
    float p = 0.f;
    #pragma unroll
    for (int i = 0; i < 4; ++i) {
      float4 kv = kr[i], qv4 = q4[i];
      p += kv.x * qv4.x + kv.y * qv4.y + kv.z * qv4.z + kv.w * qv4.w;
    }
    p += __shfl_xor(p, 1); p += __shfl_xor(p, 2);
    if (part == 0) sm.u.s.sc[r] = p * SCALEF;
  }
  __syncthreads();

  if (t < 64) {
    float v = (t < NK) ? sm.u.s.sc[t] : -1e30f;
    float mx = v;
    for (int o = 32; o; o >>= 1) mx = fmaxf(mx, __shfl_xor(mx, o));
    float e = (t < NK) ? __expf(v - mx) : 0.f;
    float sum = e;
    for (int o = 32; o; o >>= 1) sum += __shfl_xor(sum, o);
    sm.u.s.ps[t] = (t < NK) ? e / sum : 0.f;
  }
  __syncthreads();

  {
    int d = t >> 2, g4 = t & 3;
    constexpr int RPG = NK / 4;
    float yp = 0.f;
    #pragma unroll 4
    for (int rr = 0; rr < RPG; ++rr) {
      int r = g4 * RPG + rr;
      yp += sm.u.s.ps[r] * X[(size_t)(s_base + r * KSTR) * STRIDE_HD + h * DD + d];
    }
    yp += __shfl_xor(yp, 1); yp += __shfl_xor(yp, 2);
    if (g4 == 0) sm.u.s.ys[d] = yp;
  }
  __syncthreads();

  {
    int e = t >> 2, part = t & 3;
    const float4* wr = (const float4*)(Wv + (size_t)h * 4096 + e * 64 + part * 16);
    const float4* y4 = (const float4*)(sm.u.s.ys + part * 16);
    float p = 0.f;
    #pragma unroll
    for (int i = 0; i < 4; ++i) {
      float4 wv = wr[i], yv = y4[i];
      p += wv.x * yv.x + wv.y * yv.y + wv.z * yv.z + wv.w * yv.w;
    }
    p += __shfl_xor(p, 1); p += __shfl_xor(p, 2);
    if (part == 0) sm.u.s.oe[e] = p + bvv[h * 64 + e];
  }
  __syncthreads();

  if (t < 32) {
    float co = cosb[s_base * 32 + t], si = sinb[s_base * 32 + t];
    float o0 = sm.u.s.oe[2 * t], o1 = sm.u.s.oe[2 * t + 1];
    outb[(size_t)n * STRIDE_HD + h * DD + 2 * t]     = o0 * co - o1 * si;
    outb[(size_t)n * STRIDE_HD + h * DD + 2 * t + 1] = o1 * co + o0 * si;
  }
}

// v (S,H,D) f32 -> vb2[h][fk][l8][d][li] bf16 (l = l8*8+li, l>=52 zero)
__device__ void vb_path(int fk, int h, const float* __restrict__ v,
                        unsigned short* __restrict__ vb2, SvShared& sm) {
  const int tid = threadIdx.x;
  for (int idx = tid; idx < NB2 * DD; idx += 256) {
    int l = idx >> 6, d = idx & 63;
    sm.u.tile[l][d] = v[(size_t)(fk * NB2 + l) * STRIDE_HD + h * DD + d];
  }
  __syncthreads();
  for (int idx = tid; idx < 512; idx += 256) {
    int l8 = idx >> 6, d = idx & 63;
    unsigned short tmp[8];
    #pragma unroll
    for (int li = 0; li < 8; ++li) {
      int l = l8 * 8 + li;
      tmp[li] = (l < NB2) ? f2bf(sm.u.tile[l][d]) : (unsigned short)0;
    }
    bf16x8* dst = (bf16x8*)(vb2 + (((size_t)(h * FB1 + fk) * 8 + l8) * 64 + d) * 8);
    *dst = *(bf16x8*)tmp;
  }
}

__global__ __launch_bounds__(256)
void k_sv(const float* __restrict__ lk, const float* __restrict__ rq,
          const float* __restrict__ v,
          const float* __restrict__ cosb, const float* __restrict__ sinb,
          const float* __restrict__ Klg, const float* __restrict__ Krg,
          const float* __restrict__ ql, const float* __restrict__ qr,
          const float* __restrict__ W_lkv, const float* __restrict__ b_lkv,
          const float* __restrict__ W_rqv, const float* __restrict__ b_rqv,
          float* __restrict__ lk_out, float* __restrict__ rq_out,
          unsigned short* __restrict__ vb2) {
  __shared__ SvShared sm;
  const int bx = blockIdx.x;
  if (bx < 672) {
    sdpa_path<52, 56, 28, 52, 1>(bx % 56, bx / 56, lk, Klg, ql, cosb, sinb,
                                 W_lkv, b_lkv, lk_out, sm);
  } else if (bx < 1920) {
    int id = bx - 672;
    sdpa_path<28, 104, 52, 1, 52>(id % 104, id / 104, rq, Krg, qr, cosb, sinb,
                                  W_rqv, b_rqv, rq_out, sm);
  } else {
    int id = bx - 1920;
    vb_path(id % 56, id / 56, v, vb2, sm);
  }
}

// ===========================================================================
// MID (MFMA, hi/lo bf16 split), single merged launch.
// ===========================================================================
struct MgL { unsigned short Yhi[64][64];  unsigned short Ylo[64][64];
             unsigned short Xhi[64][64];  unsigned short Xlo[64][64]; };
struct MgR { unsigned short Yhi[128][64]; unsigned short Ylo[128][64];
             unsigned short Xhi[32][64];  unsigned short Xlo[32][64]; };
union MgShared { MgL L; MgR R; };

__global__ __launch_bounds__(256, 4)
void k_midg(const float* __restrict__ lq, const float* __restrict__ rk,
            const float* __restrict__ lk_out, const float* __restrict__ rq_out,
            const float* __restrict__ cosb, const float* __restrict__ sinb,
            float* __restrict__ LbufN, float* __restrict__ Rbuf) {
  __shared__ __align__(16) MgShared sh;
  const int tid = threadIdx.x;
  const int lane = tid & 63, w = tid >> 6;
  const int hi = lane >> 5, arow = lane & 31;
  int bx = blockIdx.x;

  if (bx < 552) {
    const int h = bx / 46, pt = bx % 46;
    const int rowbase = pt * 64;
    for (int idx = tid; idx < 2048; idx += 256) {           // Y (56 valid)
      int q = idx >> 5, m = idx & 31;
      float y0 = 0.f, y1 = 0.f;
      if (q < 56) {
        float2 yv = *(const float2*)(lk_out + (size_t)q * STRIDE_HD + h * DD + 2 * m);
        y0 = yv.x; y1 = yv.y;
      }
      unsigned short h0 = f2bf(y0), h1 = f2bf(y1);
      unsigned short l0 = f2bf(y0 - bf2f(h0)), l1 = f2bf(y1 - bf2f(h1));
      int ms2 = m ^ ((q & 7) << 2);
      ((unsigned*)sh.L.Yhi[q])[ms2] = (unsigned)h0 | ((unsigned)h1 << 16);
      ((unsigned*)sh.L.Ylo[q])[ms2] = (unsigned)l0 | ((unsigned)l1 << 16);
    }
    for (int idx = tid; idx < 2048; idx += 256) {           // X + rope
      int r = idx >> 5, m = idx & 31;
      int srow = rowbase + r;
      float o0 = 0.f, o1 = 0.f;
      if (srow < 2912) {
        float2 xv = *(const float2*)(lq + (size_t)srow * STRIDE_HD + h * DD + 2 * m);
        float co = cosb[srow * 32 + m], si = sinb[srow * 32 + m];
        o0 = xv.x * co - xv.y * si;
        o1 = xv.y * co + xv.x * si;
      }
      unsigned short h0 = f2bf(o0), h1 = f2bf(o1);
      unsigned short l0 = f2bf(o0 - bf2f(h0)), l1 = f2bf(o1 - bf2f(h1));
      int ms2 = m ^ ((r & 7) << 2);
      ((unsigned*)sh.L.Xhi[r])[ms2] = (unsigned)h0 | ((unsigned)h1 << 16);
      ((unsigned*)sh.L.Xlo[r])[ms2] = (unsigned)l0 | ((unsigned)l1 << 16);
    }
    __syncthreads();

    const int xt = w >> 1, qt = w & 1;
    const int brow = qt * 32 + arow;
    const int bswz = (brow & 7) << 3;
    const int xrow = xt * 32 + arow;
    const int aswz = (xrow & 7) << 3;
    f32x16 acc = {0.f,0.f,0.f,0.f,0.f,0.f,0.f,0.f,0.f,0.f,0.f,0.f,0.f,0.f,0.f,0.f};
    #pragma unroll
    for (int ks = 0; ks < 4; ++ks) {
      int kbB = (ks * 16 + hi * 8) ^ bswz;
      int kbA = (ks * 16 + hi * 8) ^ aswz;
      bf16x8 Bhi = *(const bf16x8*)&sh.L.Yhi[brow][kbB];
      bf16x8 Blo = *(const bf16x8*)&sh.L.Ylo[brow][kbB];
      bf16x8 Ahi = *(const bf16x8*)&sh.L.Xhi[xrow][kbA];
      bf16x8 Alo = *(const bf16x8*)&sh.L.Xlo[xrow][kbA];
      acc = __builtin_amdgcn_mfma_f32_32x32x16_bf16(Ahi, Bhi, acc, 0, 0, 0);
      acc = __builtin_amdgcn_mfma_f32_32x32x16_bf16(Ahi, Blo, acc, 0, 0, 0);
      acc = __builtin_amdgcn_mfma_f32_32x32x16_bf16(Alo, Bhi, acc, 0, 0, 0);
    }
    int col = qt * 32 + arow;
    if (col < 56) {
      #pragma unroll
      for (int rg = 0; rg < 16; ++rg) {
        int P = rowbase + xt * 32 + (rg & 3) + 8 * (rg >> 2) + 4 * hi;
        if (P < 2912)
          LbufN[((size_t)h * 2912 + P) * 56 + col] = acc[rg];
      }
    }
  } else {
    bx -= 552;
    const int h = bx / 91, pt = bx % 91;
    const int rowbase = pt * 32;
    for (int idx = tid; idx < 4096; idx += 256) {           // Y (104 valid)
      int q = idx >> 5, m = idx & 31;
      float y0 = 0.f, y1 = 0.f;
      if (q < 104) {
        float2 yv = *(const float2*)(rq_out + (size_t)q * STRIDE_HD + h * DD + 2 * m);
        y0 = yv.x; y1 = yv.y;
      }
      unsigned short h0 = f2bf(y0), h1 = f2bf(y1);
      unsigned short l0 = f2bf(y0 - bf2f(h0)), l1 = f2bf(y1 - bf2f(h1));
      int ms2 = m ^ ((q & 7) << 2);
      ((unsigned*)sh.R.Yhi[q])[ms2] = (unsigned)h0 | ((unsigned)h1 << 16);
      ((unsigned*)sh.R.Ylo[q])[ms2] = (unsigned)l0 | ((unsigned)l1 << 16);
    }
    for (int idx = tid; idx < 1024; idx += 256) {           // X + rope
      int r = idx >> 5, m = idx & 31;
      int srow = rowbase + r;
      float2 xv = *(const float2*)(rk + (size_t)srow * STRIDE_HD + h * DD + 2 * m);
      float co = cosb[srow * 32 + m], si = sinb[srow * 32 + m];
      float o0 = xv.x * co - xv.y * si;
      float o1 = xv.y * co + xv.x * si;
      unsigned short h0 = f2bf(o0), h1 = f2bf(o1);
      unsigned short l0 = f2bf(o0 - bf2f(h0)), l1 = f2bf(o1 - bf2f(h1));
      int ms2 = m ^ ((r & 7) << 2);
      ((unsigned*)sh.R.Xhi[r])[ms2] = (unsigned)h0 | ((unsigned)h1 << 16);
      ((unsigned*)sh.R.Xlo[r])[ms2] = (unsigned)l0 | ((unsigned)l1 << 16);
    }
    __syncthreads();

    const int brow = w * 32 + arow;
    const int bswz = (brow & 7) << 3;
    const int aswz = (arow & 7) << 3;
    f32x16 acc = {0.f,0.f,0.f,0.f,0.f,0.f,0.f,0.f,0.f,0.f,0.f,0.f,0.f,0.f,0.f,0.f};
    #pragma unroll
    for (int ks = 0; ks < 4; ++ks) {
      int kbB = (ks * 16 + hi * 8) ^ bswz;
      int kbA = (ks * 16 + hi * 8) ^ aswz;
      bf16x8 Bhi = *(const bf16x8*)&sh.R.Yhi[brow][kbB];
      bf16x8 Blo = *(const bf16x8*)&sh.R.Ylo[brow][kbB];
      bf16x8 Ahi = *(const bf16x8*)&sh.R.Xhi[arow][kbA];
      bf16x8 Alo = *(const bf16x8*)&sh.R.Xlo[arow][kbA];
      acc = __builtin_amdgcn_mfma_f32_32x32x16_bf16(Ahi, Bhi, acc, 0, 0, 0);
      acc = __builtin_amdgcn_mfma_f32_32x32x16_bf16(Ahi, Blo, acc, 0, 0, 0);
      acc = __builtin_amdgcn_mfma_f32_32x32x16_bf16(Alo, Bhi, acc, 0, 0, 0);
    }
    int cq = w * 32 + arow;
    if (cq < 104) {
      int aa = (cq >= 52) ? 1 : 0;
      int jj = cq - aa * 52;
      float* rowp = Rbuf + ((size_t)((h * 2 + aa) * 52 + jj)) * 2912 + rowbase + 4 * hi;
      #pragma unroll
      for (int q4 = 0; q4 < 4; ++q4) {
        f32x4 res = {acc[4 * q4], acc[4 * q4 + 1], acc[4 * q4 + 2], acc[4 * q4 + 3]};
        *(f32x4*)(rowp + 8 * q4) = res;
      }
    }
  }
}

// ===========================================================================
// MAIN: factorized flash attention, 1 j per block, L in registers, slim LDS,
// V half-tile rolling double buffer (max 8 fragments live = 32 VGPR).
// ===========================================================================
__device__ __forceinline__ bf16x8 make_p8(float Lv, float nm, float4 ra, float4 rb,
                                          int ks, int hi, float& lsum) {
  float p0 = EXP2(fmaf(Lv, ra.x, nm));
  float p1 = EXP2(fmaf(Lv, ra.y, nm));
  float p2 = EXP2(fmaf(Lv, ra.z, nm));
  float p3 = EXP2(fmaf(Lv, ra.w, nm));
  float p4 = EXP2(fmaf(Lv, rb.x, nm));
  float p5 = EXP2(fmaf(Lv, rb.y, nm));
  float p6 = EXP2(fmaf(Lv, rb.z, nm));
  float p7 = EXP2(fmaf(Lv, rb.w, nm));
  if (ks == 3) {
    if (hi == 0) { p4 = 0.f; p5 = 0.f; p6 = 0.f; p7 = 0.f; }
    else { p0 = 0.f; p1 = 0.f; p2 = 0.f; p3 = 0.f;
           p4 = 0.f; p5 = 0.f; p6 = 0.f; p7 = 0.f; }
  }
  lsum += ((p0 + p1) + (p2 + p3)) + ((p4 + p5) + (p6 + p7));
  union { bf16x8 v8; __hip_bfloat162 h2[4]; } pk;
  pk.h2[0] = __float22bfloat162_rn(make_float2(p0, p1));
  pk.h2[1] = __float22bfloat162_rn(make_float2(p2, p3));
  pk.h2[2] = __float22bfloat162_rn(make_float2(p4, p5));
  pk.h2[3] = __float22bfloat162_rn(make_float2(p6, p7));
  return pk.v8;
}

__global__ __launch_bounds__(256, 4)
void k_main(const float* __restrict__ LbufN, const float* __restrict__ Rbuf,
            const unsigned short* __restrict__ vb2, float* __restrict__ outp) {
  const int bid0 = blockIdx.x;
  const int bid = (bid0 & 7) * 156 + (bid0 >> 3);   // 1248 = 8*156, XCD-chunked
  const int h = bid / (NF * NB2);
  const int rem = bid % (NF * NB2);
  const int a = rem / NB2, j = rem % NB2;
  const int tid = threadIdx.x;
  const int lane = tid & 63;
  const int w = tid >> 6;
  const int row = lane & 31;
  const int hi = lane >> 5;

  __shared__ __align__(16) union { float Rs[56][64]; float epil[4][16][64]; } ms;
  __shared__ float Rmx[FB1], Rmn[FB1], pmax[4][32], els[4][32];

  // Rs staging (52 valid l per fk; 52..63 garbage, masked at ks==3)
  const float* Rrow = Rbuf + ((size_t)(h * 2 + a) * 52 + j) * 2912;
  for (int idx = tid; idx < 728; idx += 256) {
    int fk = idx / 13, lc = idx % 13;
    float4 vv = ((const float4*)Rrow)[idx];
    *(float4*)&ms.Rs[fk][lc * 4] = vv;
  }
  __syncthreads();

  if (tid < 224) {                                  // col max/min of R
    int fk = tid >> 2, part = tid & 3;
    float mx = -1e30f, mn = 1e30f;
    for (int l = part * 13; l < part * 13 + 13; ++l) {
      float x = ms.Rs[fk][l];
      mx = fmaxf(mx, x); mn = fminf(mn, x);
    }
    mx = fmaxf(mx, __shfl_xor(mx, 1)); mn = fminf(mn, __shfl_xor(mn, 1));
    mx = fmaxf(mx, __shfl_xor(mx, 2)); mn = fminf(mn, __shfl_xor(mn, 2));
    if (part == 0) { Rmx[fk] = mx; Rmn[fk] = mn; }
  }

  // L values for this lane's row, this wave's 14 fk's (registers)
  const float SC = SCALEF * 1.44269504f;
  float Lv[14];
  {
    const float* Lrow = LbufN + ((size_t)h * 2912 + a * 1456 + row * 52 + j) * 56 + w * 14;
    #pragma unroll
    for (int t = 0; t < 14; ++t)
      Lv[t] = (row < NB1) ? Lrow[t] * SC : 0.f;
  }
  __syncthreads();                                  // Rmx/Rmn ready

  // exact row max: per-lane partial over 14 fk, combine across 4 waves
  {
    float pm = -1e30f;
    #pragma unroll
    for (int t = 0; t < 14; ++t) {
      int fk = w * 14 + t;
      pm = fmaxf(pm, fmaxf(Lv[t] * Rmx[fk], Lv[t] * Rmn[fk]));
    }
    if (hi == 0) pmax[w][row] = pm;
  }
  __syncthreads();
  const float m2 = fmaxf(fmaxf(pmax[0][row], pmax[1][row]),
                         fmaxf(pmax[2][row], pmax[3][row]));
  const float nm = -m2;

  const bf16x8* vw = (const bf16x8*)vb2 + (size_t)h * 28672 + hi * 64 + row;

  f32x16 acc0 = {0.f,0.f,0.f,0.f,0.f,0.f,0.f,0.f,0.f,0.f,0.f,0.f,0.f,0.f,0.f,0.f};
  f32x16 acc1 = acc0;
  float lsum = 0.f;

#define KSTEP(T, KS, V0, V1)                                                    \
  {                                                                             \
    const int fk_ = w * 14 + (T);                                               \
    const int k0_ = (KS) * 16 + hi * 8;                                         \
    float4 ra = *(const float4*)&ms.Rs[fk_][k0_];                               \
    float4 rb = *(const float4*)&ms.Rs[fk_][k0_ + 4];                           \
    bf16x8 pk = make_p8(Lv[(T)], nm, ra, rb, (KS), hi, lsum);                   \
    acc0 = __builtin_amdgcn_mfma_f32_32x32x16_bf16(pk, V0, acc0, 0, 0, 0);      \
    acc1 = __builtin_amdgcn_mfma_f32_32x32x16_bf16(pk, V1, acc1, 0, 0, 0);      \
  }

  {
    bf16x8 A0, A1, A2, A3, B0, B1, B2, B3;
    {
      const bf16x8* vp_ = vw + (size_t)(w * 14) * 512;
      A0 = vp_[0]; A1 = vp_[32]; A2 = vp_[128]; A3 = vp_[160];   // tile0 ks01
    }
    #pragma unroll
    for (int t = 0; t < 14; ++t) {
      {
        const bf16x8* vp_ = vw + (size_t)(w * 14 + t) * 512;
        B0 = vp_[256]; B1 = vp_[288]; B2 = vp_[384]; B3 = vp_[416]; // tile t ks23
      }
      KSTEP(t, 0, A0, A1)
      KSTEP(t, 1, A2, A3)
      if (t + 1 < 14) {
        const bf16x8* vn_ = vw + (size_t)(w * 14 + t + 1) * 512;
        A0 = vn_[0]; A1 = vn_[32]; A2 = vn_[128]; A3 = vn_[160];   // tile t+1 ks01
      }
      KSTEP(t, 2, B0, B1)
      KSTEP(t, 3, B2, B3)
    }
  }
#undef KSTEP

  lsum += __shfl_xor(lsum, 32);
  if (lane < 32) els[w][lane] = lsum;
  __syncthreads();                                  // Rs reads done; els visible

  // epilogue: 2 rounds (d-halves) of 4-segment reduction through LDS
  #pragma unroll
  for (int half = 0; half < 2; ++half) {
    if (half) __syncthreads();
    #pragma unroll
    for (int r = 0; r < 16; ++r)
      ms.epil[w][r][lane] = half ? acc1[r] : acc0[r];
    __syncthreads();
    #pragma unroll
    for (int q = 0; q < 4; ++q) {
      int r = w + q * 4;
      int elane = tid & 63;
      float val = ms.epil[0][r][elane] + ms.epil[1][r][elane]
                + ms.epil[2][r][elane] + ms.epil[3][r][elane];
      int irow = (r & 3) + 8 * (r >> 2) + 4 * (elane >> 5);
      if (irow < NB1) {
        float li = 1.0f / (els[0][irow] + els[1][irow] + els[2][irow] + els[3][irow]);
        int srow = a * (NB1 * NB2) + irow * NB2 + j;
        int d = half * 32 + (elane & 31);
        outp[(size_t)srow * STRIDE_HD + h * DD + d] = val * li;
      }
    }
  }
}

// ---------------------------------------------------------------------------
extern "C" void kernel_launch(void* const* d_in, const int* in_sizes, int n_in,
                              void* d_out, int out_size, void* d_ws, size_t ws_size,
                              hipStream_t stream) {
  (void)in_sizes; (void)n_in; (void)out_size; (void)ws_size;
  const float* lq   = (const float*)d_in[0];
  const float* lk   = (const float*)d_in[1];
  const float* rq   = (const float*)d_in[2];
  const float* rk   = (const float*)d_in[3];
  const float* v    = (const float*)d_in[4];
  const float* cosb = (const float*)d_in[5];
  const float* sinb = (const float*)d_in[6];
  const float* W_lkq = (const float*)d_in[7];  const float* b_lkq = (const float*)d_in[8];
  const float* W_lkk = (const float*)d_in[9];  const float* b_lkk = (const float*)d_in[10];
  const float* W_lkv = (const float*)d_in[11]; const float* b_lkv = (const float*)d_in[12];
  const float* W_rqq = (const float*)d_in[13]; const float* b_rqq = (const float*)d_in[14];
  const float* W_rqk = (const float*)d_in[15]; const float* b_rqk = (const float*)d_in[16];
  const float* W_rqv = (const float*)d_in[17]; const float* b_rqv = (const float*)d_in[18];

  float* ws = (float*)d_ws;
  float* lk_out = ws;                                   // 43008
  float* rq_out = ws + 43008;                           // 79872
  float* LbufN  = ws + 122880;                          // 1956864 (12*2912*56)
  float* Rbuf   = ws + 2079744;                         // 3634176
  unsigned short* vb2 = (unsigned short*)(ws + 5713920);// 2752512 shorts
  float* ql     = ws + 7090176;                         // 43008
  float* qr     = ws + 7133184;                         // 79872
  // Klg/Krg alias the LbufN/Rbuf space (dead before k_midg writes them)
  float* Klg = LbufN;                                   // 2236416
  float* Krg = LbufN + 2236416;                         // 2236416 (ends < Rbuf end)

  k_proj<<<1140, 256, 0, stream>>>(lk, rq, cosb, sinb,
      W_lkk, b_lkk, W_rqk, b_rqk, W_lkq, b_lkq, W_rqq, b_rqq,
      Klg, Krg, ql, qr);
  k_sv<<<2592, 256, 0, stream>>>(lk, rq, v, cosb, sinb, Klg, Krg, ql, qr,
      W_lkv, b_lkv, W_rqv, b_rqv, lk_out, rq_out, vb2);
  k_midg<<<1644, 256, 0, stream>>>(lq, rk, lk_out, rq_out, cosb, sinb, LbufN, Rbuf);
  k_main<<<1248, 256, 0, stream>>>(LbufN, Rbuf, vb2, (float*)d_out);
}